// Round 4
// baseline (7331.969 us; speedup 1.0000x reference)
//
#include <hip/hip_runtime.h>
#include <cstddef>
#include <cstdint>

#define NB 2

// Nmax per resolution (upper bounds on active sites, both batches)
#define NMAX512 32768
#define NMAX256 28672
#define NMAX128 20480
#define NMAX64  8192
#define NMAX32  2048

// ------------------------------------------------------------------ list build (res 512 from x, Cin=1)
__global__ __launch_bounds__(256) void build_l0_k(const float* __restrict__ x,
    int* __restrict__ list, int* __restrict__ im, float* __restrict__ f0,
    int* __restrict__ nact, int total, int nmax) {
  int i = blockIdx.x * 256 + threadIdx.x;
  bool act = false;
  float v = 0.f;
  if (i < total) { v = x[i]; act = (v != 0.f); }
  unsigned long long mb = __ballot(act);
  int lane = threadIdx.x & 63;
  int prefix = __popcll(mb & ((1ull << lane) - 1));
  int base = 0;
  if (lane == 0) base = atomicAdd(nact, __popcll(mb));
  base = __shfl(base, 0);
  if (i < total) {
    int idx = act ? (base + prefix) : -1;
    if (idx >= nmax) idx = -1;
    im[i] = idx;
    if (idx >= 0) {
      int b = i >> 18;            // 512*512 = 2^18
      int rem = i & 262143;
      list[idx] = (b << 20) | ((rem >> 9) << 10) | (rem & 511);
      f0[idx] = v;
    }
  }
}

// ------------------------------------------------------------------ pooled list from finer idxmap
__global__ __launch_bounds__(256) void build_pl_k(const int* __restrict__ imF,
    int* __restrict__ list, int* __restrict__ im, int* __restrict__ nact,
    int Hc, int nmax) {
  int total = NB * Hc * Hc;
  int i = blockIdx.x * 256 + threadIdx.x;
  bool act = false;
  int b = 0, y = 0, x = 0;
  int Hf = Hc * 2;
  if (i < total) {
    x = i % Hc; y = (i / Hc) % Hc; b = i / (Hc * Hc);
    const int* p = imF + ((size_t)b * Hf + 2 * y) * Hf + 2 * x;
    act = (p[0] >= 0) || (p[1] >= 0) || (p[Hf] >= 0) || (p[Hf + 1] >= 0);
  }
  unsigned long long mb = __ballot(act);
  int lane = threadIdx.x & 63;
  int prefix = __popcll(mb & ((1ull << lane) - 1));
  int base = 0;
  if (lane == 0) base = atomicAdd(nact, __popcll(mb));
  base = __shfl(base, 0);
  if (i < total) {
    int idx = act ? (base + prefix) : -1;
    if (idx >= nmax) idx = -1;
    im[i] = idx;
    if (idx >= 0) list[idx] = (b << 20) | (y << 10) | x;
  }
}

// ------------------------------------------------------------------ 9-neighbor index table
__global__ __launch_bounds__(256) void build_nbr_k(const int* __restrict__ list,
    const int* __restrict__ im, const int* __restrict__ nactp,
    int* __restrict__ nbr, int H, int nmax) {
  int i = blockIdx.x * 256 + threadIdx.x;
  if (i >= nactp[0]) return;
  int code = list[i];
  int b = code >> 20, y = (code >> 10) & 1023, x = code & 1023;
#pragma unroll
  for (int k = 0; k < 9; ++k) {
    int yy = y + k / 3 - 1, xx = x + k % 3 - 1;
    int v = -1;
    if (yy >= 0 && yy < H && xx >= 0 && xx < H)
      v = im[((size_t)b * H + yy) * H + xx];
    nbr[k * nmax + i] = v;
  }
}

// ------------------------------------------------------------------ weight transpose  [R][C] -> [C][R]
__global__ __launch_bounds__(256) void transpose_k(const float* __restrict__ in,
                                                   float* __restrict__ out,
                                                   int R, int C) {
  __shared__ float tile[32][33];
  int bx = blockIdx.x * 32;  // col base (C dim)
  int by = blockIdx.y * 32;  // row base (R dim)
  int tx = threadIdx.x % 32, ty0 = threadIdx.x / 32;
  for (int ty = ty0; ty < 32; ty += 8) {
    int r = by + ty, c = bx + tx;
    tile[ty][tx] = (r < R && c < C) ? in[(size_t)r * C + c] : 0.f;
  }
  __syncthreads();
  for (int ty = ty0; ty < 32; ty += 8) {
    int r = bx + ty, c = by + tx;
    if (r < C && c < R) out[(size_t)r * R + c] = tile[tx][ty];
  }
}

// ------------------------------------------------------------------ gather-GEMM submanifold conv
// Block: SITES sites x OCB out-channels; thread: SPT sites x OPT oc.
// OPT==8 split-oc: thread owns {oc0..+3} u {OCB/2+oc0..+3} -> wave LDS reads
// are contiguous 16B chunks (<=2-way alias = free).
// SPT==8: a-read is 2x b128 (broadcast across oc-groups).
// XCD swizzle: gid=(sbg*nocb+ocbI)*8+xcd so all panels/K-splits of one
// site-block share gid mod 8 (same XCD L2).
// RAW: raw partial over cin slice [z*cinCnt,(z+1)*cinCnt) -> out + z*Nmax*Cout
template <int CC, int SITES, int OCB, int SPT, int OPT, bool RAW>
__global__ __launch_bounds__(256, 3) void gconv_k(
    const float* __restrict__ in, float* __restrict__ out,
    const float* __restrict__ wT, const float* __restrict__ bias,
    const int* __restrict__ nbr, const int* __restrict__ nactp,
    int Cin, int Cout, int Nmax, int cinCnt, int nocb) {
  constexpr int KSL = CC * 9;
  __shared__ int s_nbr[9][SITES];
  __shared__ float s_a[KSL][SITES];
  __shared__ float s_w[KSL][OCB];
  const int n = nactp[0];
  const int gid = blockIdx.x;
  const int xcd = gid & 7;
  const int pos = gid >> 3;
  const int ocbI = pos % nocb;
  const int sb = (pos / nocb) * 8 + xcd;
  const int base = sb * SITES;
  if (base >= n) return;
  const int ocb = ocbI * OCB;
  const int t = threadIdx.x;
  for (int s = t; s < 9 * SITES; s += 256) {
    int i = s % SITES, k = s / SITES;
    int gi = base + i;
    s_nbr[k][i] = (gi < n) ? nbr[k * Nmax + gi] : -1;
  }
  constexpr int OCG = OCB / OPT;
  const int oc0 = (t % OCG) * 4;           // 4-float chunk base
  const int si0 = (t / OCG) * SPT;
  float acc[SPT][OPT];
#pragma unroll
  for (int a = 0; a < SPT; ++a)
#pragma unroll
    for (int j = 0; j < OPT; ++j) acc[a][j] = 0.f;
  __syncthreads();
  const int cinStart = RAW ? (blockIdx.z * cinCnt) : 0;
  const int nch = cinCnt / CC;
  for (int ch = 0; ch < nch; ++ch) {
    const int c0 = cinStart + ch * CC;
    // ---- stage weights: KSL contiguous rows of wT starting at row c0*9 (float4)
    const float* wrow = wT + ((size_t)c0 * 9) * Cout + ocb;
    for (int s = t; s < KSL * (OCB / 4); s += 256) {
      int j4 = s % (OCB / 4), r = s / (OCB / 4);
      *(float4*)&s_w[r][j4 * 4] = *(const float4*)(wrow + (size_t)r * Cout + j4 * 4);
    }
    // ---- stage gathered A tile
    if constexpr (CC == 1) {
      for (int s = t; s < 9 * SITES; s += 256) {
        int i = s % SITES, k = s / SITES;
        int row = s_nbr[k][i];
        s_a[k][i] = (row >= 0) ? in[row] : 0.f;
      }
    } else {
      constexpr int H4 = CC / 4;
      for (int s = t; s < H4 * 9 * SITES; s += 256) {
        int i = s % SITES, m = s / SITES;
        int c4 = m % H4, k = m / H4;
        int row = s_nbr[k][i];
        float4 v = make_float4(0.f, 0.f, 0.f, 0.f);
        if (row >= 0)
          v = *(const float4*)(in + (size_t)row * Cin + c0 + c4 * 4);
        s_a[(c4 * 4 + 0) * 9 + k][i] = v.x;
        s_a[(c4 * 4 + 1) * 9 + k][i] = v.y;
        s_a[(c4 * 4 + 2) * 9 + k][i] = v.z;
        s_a[(c4 * 4 + 3) * 9 + k][i] = v.w;
      }
    }
    __syncthreads();
    // ---- MAC
#pragma unroll
    for (int kk = 0; kk < KSL; ++kk) {
      float av[SPT];
      if constexpr (SPT == 8) {
        float4 a0 = *(const float4*)&s_a[kk][si0];
        float4 a1 = *(const float4*)&s_a[kk][si0 + 4];
        av[0] = a0.x; av[1] = a0.y; av[2] = a0.z; av[3] = a0.w;
        av[4] = a1.x; av[5] = a1.y; av[6] = a1.z; av[7] = a1.w;
      } else if constexpr (SPT == 4) {
        float4 a4 = *(const float4*)&s_a[kk][si0];
        av[0] = a4.x; av[1] = a4.y; av[2] = a4.z; av[3] = a4.w;
      } else {
        float2 a2 = *(const float2*)&s_a[kk][si0];
        av[0] = a2.x; av[1] = a2.y;
      }
      float wv[OPT];
      if constexpr (OPT == 8) {
        float4 w4a = *(const float4*)&s_w[kk][oc0];
        float4 w4b = *(const float4*)&s_w[kk][OCB / 2 + oc0];
        wv[0] = w4a.x; wv[1] = w4a.y; wv[2] = w4a.z; wv[3] = w4a.w;
        wv[4] = w4b.x; wv[5] = w4b.y; wv[6] = w4b.z; wv[7] = w4b.w;
      } else {
        float4 w4 = *(const float4*)&s_w[kk][oc0];
        wv[0] = w4.x; wv[1] = w4.y; wv[2] = w4.z; wv[3] = w4.w;
      }
#pragma unroll
      for (int a = 0; a < SPT; ++a)
#pragma unroll
        for (int j = 0; j < OPT; ++j)
          acc[a][j] = fmaf(av[a], wv[j], acc[a][j]);
    }
    __syncthreads();
  }
  // ---- epilogue
  float bz[OPT];
  if constexpr (!RAW) {
#pragma unroll
    for (int j = 0; j < OPT; ++j) {
      int oj = (OPT == 8) ? ((j < 4) ? (oc0 + j) : (OCB / 2 + oc0 + j - 4))
                          : (oc0 + j);
      bz[j] = bias[ocb + oj];
    }
  }
  float* ob = out;
  if constexpr (RAW) ob += (size_t)blockIdx.z * Nmax * Cout;
#pragma unroll
  for (int a = 0; a < SPT; ++a) {
    int gi = base + si0 + a;
    if (gi < n) {
      float* po = ob + (size_t)gi * Cout + ocb;
      if constexpr (OPT == 8) {
        float4 v0, v1;
        if constexpr (RAW) {
          v0 = make_float4(acc[a][0], acc[a][1], acc[a][2], acc[a][3]);
          v1 = make_float4(acc[a][4], acc[a][5], acc[a][6], acc[a][7]);
        } else {
          v0.x = fmaxf(acc[a][0] + bz[0], 0.f); v0.y = fmaxf(acc[a][1] + bz[1], 0.f);
          v0.z = fmaxf(acc[a][2] + bz[2], 0.f); v0.w = fmaxf(acc[a][3] + bz[3], 0.f);
          v1.x = fmaxf(acc[a][4] + bz[4], 0.f); v1.y = fmaxf(acc[a][5] + bz[5], 0.f);
          v1.z = fmaxf(acc[a][6] + bz[6], 0.f); v1.w = fmaxf(acc[a][7] + bz[7], 0.f);
        }
        *(float4*)(po + oc0) = v0;
        *(float4*)(po + OCB / 2 + oc0) = v1;
      } else {
        float4 v;
        if constexpr (RAW) {
          v = make_float4(acc[a][0], acc[a][1], acc[a][2], acc[a][3]);
        } else {
          v.x = fmaxf(acc[a][0] + bz[0], 0.f); v.y = fmaxf(acc[a][1] + bz[1], 0.f);
          v.z = fmaxf(acc[a][2] + bz[2], 0.f); v.w = fmaxf(acc[a][3] + bz[3], 0.f);
        }
        *(float4*)(po + oc0) = v;
      }
    }
  }
}

// ------------------------------------------------------------------ K-split combine (+bias+relu)
__global__ __launch_bounds__(256) void combine_k(const float* __restrict__ P,
    float* __restrict__ out, const float* __restrict__ bias,
    const int* __restrict__ nactp, int C, int S, int sliceStride) {
  int tg = blockIdx.x * 256 + threadIdx.x;
  int cg = C >> 2;
  int j = tg / cg, c4 = tg % cg;
  if (j >= nactp[0]) return;
  size_t o = (size_t)j * C + c4 * 4;
  float4 v = *(const float4*)(bias + c4 * 4);
  for (int s = 0; s < S; ++s) {
    float4 u = *(const float4*)(P + (size_t)s * sliceStride + o);
    v.x += u.x; v.y += u.y; v.z += u.z; v.w += u.w;
  }
  v.x = fmaxf(v.x, 0.f); v.y = fmaxf(v.y, 0.f);
  v.z = fmaxf(v.z, 0.f); v.w = fmaxf(v.w, 0.f);
  *(float4*)(out + o) = v;
}

// ------------------------------------------------------------------ compact 2x2 maxpool
__global__ __launch_bounds__(256) void pool_c_k(const float* __restrict__ inF,
    float* __restrict__ outF, const int* __restrict__ listC,
    const int* __restrict__ imF, const int* __restrict__ nactp, int Hf, int C) {
  int tg = blockIdx.x * 256 + threadIdx.x;
  int cg = C >> 2;
  int j = tg / cg, c4 = tg % cg;
  if (j >= nactp[0]) return;
  int code = listC[j];
  int b = code >> 20, Y = (code >> 10) & 1023, X = code & 1023;
  float4 v = make_float4(0.f, 0.f, 0.f, 0.f);
#pragma unroll
  for (int dy = 0; dy < 2; ++dy)
#pragma unroll
    for (int dx = 0; dx < 2; ++dx) {
      int ci = imF[((size_t)b * Hf + 2 * Y + dy) * Hf + 2 * X + dx];
      if (ci >= 0) {
        float4 u = *(const float4*)(inF + (size_t)ci * C + c4 * 4);
        v.x = fmaxf(v.x, u.x); v.y = fmaxf(v.y, u.y);
        v.z = fmaxf(v.z, u.z); v.w = fmaxf(v.w, u.w);
      }
    }
  *(float4*)(outF + (size_t)j * C + c4 * 4) = v;
}

// ------------------------------------------------------------------ final pool -> dense [2,512,16,16]
__global__ __launch_bounds__(256) void pool_d_k(const float* __restrict__ inF,
    float* __restrict__ outD, const int* __restrict__ im32) {
  int tg = blockIdx.x * 256 + threadIdx.x;  // 2*16*16*128 = 65536
  int c4 = tg & 127;
  int rest = tg >> 7;
  int X = rest & 15, Y = (rest >> 4) & 15, b = rest >> 8;
  float4 v = make_float4(0.f, 0.f, 0.f, 0.f);
#pragma unroll
  for (int dy = 0; dy < 2; ++dy)
#pragma unroll
    for (int dx = 0; dx < 2; ++dx) {
      int ci = im32[((size_t)b * 32 + 2 * Y + dy) * 32 + 2 * X + dx];
      if (ci >= 0) {
        float4 u = *(const float4*)(inF + (size_t)ci * 512 + c4 * 4);
        v.x = fmaxf(v.x, u.x); v.y = fmaxf(v.y, u.y);
        v.z = fmaxf(v.z, u.z); v.w = fmaxf(v.w, u.w);
      }
    }
  const float* pv = &v.x;
#pragma unroll
  for (int u = 0; u < 4; ++u) {
    int c = c4 * 4 + u;
    outD[(((size_t)b * 512 + c) * 16 + Y) * 16 + X] = pv[u];
  }
}

// ------------------------------------------------------------------ fully connected
template <bool RELU>
__global__ __launch_bounds__(256) void fc_k(const float* __restrict__ in,
                                            const float* __restrict__ w,
                                            const float* __restrict__ bias,
                                            float* __restrict__ out, int K,
                                            int R) {
  const int r = blockIdx.x;
  const int t = threadIdx.x;
  const float* wr = w + (size_t)r * K;
  float a0 = 0.f, a1 = 0.f;
  for (int k = t * 4; k < K; k += 1024) {
    float4 wv = *(const float4*)(wr + k);
    float4 x0 = *(const float4*)(in + k);
    float4 x1 = *(const float4*)(in + K + k);
    a0 += wv.x * x0.x + wv.y * x0.y + wv.z * x0.z + wv.w * x0.w;
    a1 += wv.x * x1.x + wv.y * x1.y + wv.z * x1.z + wv.w * x1.w;
  }
#pragma unroll
  for (int off = 32; off > 0; off >>= 1) {
    a0 += __shfl_down(a0, off);
    a1 += __shfl_down(a1, off);
  }
  __shared__ float s0[4], s1[4];
  const int lane = t & 63, wid = t >> 6;
  if (lane == 0) { s0[wid] = a0; s1[wid] = a1; }
  __syncthreads();
  if (t == 0) {
    float v0 = s0[0] + s0[1] + s0[2] + s0[3] + bias[r];
    float v1 = s1[0] + s1[1] + s1[2] + s1[3] + bias[r];
    if (RELU) { v0 = fmaxf(v0, 0.f); v1 = fmaxf(v1, 0.f); }
    out[r] = v0;
    out[R + r] = v1;
  }
}

// ------------------------------------------------------------------ launch
extern "C" void kernel_launch(void* const* d_in, const int* in_sizes, int n_in,
                              void* d_out, int out_size, void* d_ws,
                              size_t ws_size, hipStream_t stream) {
  (void)in_sizes; (void)n_in; (void)out_size; (void)ws_size;
  const float* x = (const float*)d_in[0];
  const float* Wc[14];
  const float* Bc[14];
  for (int i = 1; i <= 13; ++i) {
    Wc[i] = (const float*)d_in[2 * i - 1];
    Bc[i] = (const float*)d_in[2 * i];
  }
  const float* fw1 = (const float*)d_in[27];
  const float* fb1 = (const float*)d_in[28];
  const float* fw2 = (const float*)d_in[29];
  const float* fb2 = (const float*)d_in[30];
  const float* fw3 = (const float*)d_in[31];
  const float* fb3 = (const float*)d_in[32];
  const float* fw4 = (const float*)d_in[33];
  const float* fb4 = (const float*)d_in[34];

  static const int CH[14] = {1, 64, 64, 128, 128, 256, 256, 256,
                             512, 512, 512, 512, 512, 512};

  char* ws = (char*)d_ws;
  size_t cur = 0;
  auto alloc = [&](size_t bytes) {
    size_t o = cur;
    cur += (bytes + 255) & ~(size_t)255;
    return o;
  };
  // weight transposes
  size_t wtOff[14];
  for (int i = 1; i <= 13; ++i)
    wtOff[i] = alloc((size_t)CH[i] * CH[i - 1] * 9 * 4);
  float* wT[14];
  for (int i = 1; i <= 13; ++i) wT[i] = (float*)(ws + wtOff[i]);
  // features. The A1..A6 region (dead after its layer) is reused as Praw for
  // K-split partials of L5..L13:
  //   L5/L6/L7 need 2*NMAX128*256*4 = 42MB  (A1..A4 span 53.5MB, dead then)
  //   L8       need 2*NMAX64*512*4  = 33.5MB
  //   L9/L10   need 4*NMAX64*512*4  = 67MB  (A1..A5 span >85MB, dead then)
  //   L11-13   need 8*NMAX32*512*4  = 33.5MB
  float* F0  = (float*)(ws + alloc((size_t)NMAX512 * 1 * 4));
  size_t a1Off = alloc((size_t)NMAX512 * 64 * 4);
  float* A1  = (float*)(ws + a1Off);
  float* Praw = A1;  // aliased scratch for K-split partials (see above)
  float* A2  = (float*)(ws + alloc((size_t)NMAX512 * 64 * 4));
  float* P2  = (float*)(ws + alloc((size_t)NMAX256 * 64 * 4));
  float* A3  = (float*)(ws + alloc((size_t)NMAX256 * 128 * 4));
  float* A4  = (float*)(ws + alloc((size_t)NMAX256 * 128 * 4));
  float* P4  = (float*)(ws + alloc((size_t)NMAX128 * 128 * 4));
  float* A5  = (float*)(ws + alloc((size_t)NMAX128 * 256 * 4));
  float* A6  = (float*)(ws + alloc((size_t)NMAX128 * 256 * 4));
  float* P7  = (float*)(ws + alloc((size_t)NMAX64 * 256 * 4));
  float* A8  = (float*)(ws + alloc((size_t)NMAX64 * 512 * 4));
  float* A9  = (float*)(ws + alloc((size_t)NMAX64 * 512 * 4));
  float* P10 = (float*)(ws + alloc((size_t)NMAX32 * 512 * 4));
  float* A11 = (float*)(ws + alloc((size_t)NMAX32 * 512 * 4));
  float* D13 = (float*)(ws + alloc((size_t)NB * 512 * 16 * 16 * 4));
  float* F1  = (float*)(ws + alloc(NB * 1024 * 4));
  float* F2  = (float*)(ws + alloc(NB * 512 * 4));
  float* F3  = (float*)(ws + alloc(NB * 256 * 4));
  // index maps / lists / neighbor tables / counters
  int* im512 = (int*)(ws + alloc((size_t)NB * 512 * 512 * 4));
  int* im256 = (int*)(ws + alloc((size_t)NB * 256 * 256 * 4));
  int* im128 = (int*)(ws + alloc((size_t)NB * 128 * 128 * 4));
  int* im64  = (int*)(ws + alloc((size_t)NB * 64 * 64 * 4));
  int* im32  = (int*)(ws + alloc((size_t)NB * 32 * 32 * 4));
  int* l512 = (int*)(ws + alloc((size_t)NMAX512 * 4));
  int* l256 = (int*)(ws + alloc((size_t)NMAX256 * 4));
  int* l128 = (int*)(ws + alloc((size_t)NMAX128 * 4));
  int* l64  = (int*)(ws + alloc((size_t)NMAX64 * 4));
  int* l32  = (int*)(ws + alloc((size_t)NMAX32 * 4));
  int* nb512 = (int*)(ws + alloc((size_t)9 * NMAX512 * 4));
  int* nb256 = (int*)(ws + alloc((size_t)9 * NMAX256 * 4));
  int* nb128 = (int*)(ws + alloc((size_t)9 * NMAX128 * 4));
  int* nb64  = (int*)(ws + alloc((size_t)9 * NMAX64 * 4));
  int* nb32  = (int*)(ws + alloc((size_t)9 * NMAX32 * 4));
  int* nact = (int*)(ws + alloc(256));  // [0..4] per-resolution counts

  const dim3 blk(256);
  hipMemsetAsync(nact, 0, 32, stream);

  // ---- lists / index maps / neighbors
  hipLaunchKernelGGL(build_l0_k, dim3(2048), blk, 0, stream, x, l512, im512, F0, nact + 0, NB * 512 * 512, NMAX512);
  hipLaunchKernelGGL(build_pl_k, dim3(512), blk, 0, stream, im512, l256, im256, nact + 1, 256, NMAX256);
  hipLaunchKernelGGL(build_pl_k, dim3(128), blk, 0, stream, im256, l128, im128, nact + 2, 128, NMAX128);
  hipLaunchKernelGGL(build_pl_k, dim3(32), blk, 0, stream, im128, l64, im64, nact + 3, 64, NMAX64);
  hipLaunchKernelGGL(build_pl_k, dim3(8), blk, 0, stream, im64, l32, im32, nact + 4, 32, NMAX32);
  hipLaunchKernelGGL(build_nbr_k, dim3(NMAX512 / 256), blk, 0, stream, l512, im512, nact + 0, nb512, 512, NMAX512);
  hipLaunchKernelGGL(build_nbr_k, dim3(NMAX256 / 256), blk, 0, stream, l256, im256, nact + 1, nb256, 256, NMAX256);
  hipLaunchKernelGGL(build_nbr_k, dim3(NMAX128 / 256), blk, 0, stream, l128, im128, nact + 2, nb128, 128, NMAX128);
  hipLaunchKernelGGL(build_nbr_k, dim3(NMAX64 / 256), blk, 0, stream, l64, im64, nact + 3, nb64, 64, NMAX64);
  hipLaunchKernelGGL(build_nbr_k, dim3(NMAX32 / 256), blk, 0, stream, l32, im32, nact + 4, nb32, 32, NMAX32);

  // ---- weight transposes: w[Cout][Cin*9] -> wT[Cin*9][Cout]
  for (int i = 1; i <= 13; ++i) {
    int R = CH[i], C = CH[i - 1] * 9;
    hipLaunchKernelGGL(transpose_k, dim3((C + 31) / 32, (R + 31) / 32), blk, 0,
                       stream, Wc[i], wT[i], R, C);
  }

  // ---- convs
  // L1: 1->64 @512
  hipLaunchKernelGGL((gconv_k<1, 64, 64, 4, 4, false>), dim3(512, 1, 1), blk, 0, stream,
                     F0, A1, wT[1], Bc[1], nb512, nact + 0, 1, 64, NMAX512, 1, 1);
  // L2: 64->64 @512
  hipLaunchKernelGGL((gconv_k<8, 64, 64, 4, 4, false>), dim3(512, 1, 1), blk, 0, stream,
                     A1, A2, wT[2], Bc[2], nb512, nact + 0, 64, 64, NMAX512, 64, 1);
  hipLaunchKernelGGL(pool_c_k, dim3(NMAX256 * 16 / 256), blk, 0, stream, A2, P2, l256, im512, nact + 1, 512, 64);
  // L3: 64->128 @256
  hipLaunchKernelGGL((gconv_k<8, 64, 128, 4, 8, false>), dim3(448, 1, 1), blk, 0, stream,
                     P2, A3, wT[3], Bc[3], nb256, nact + 1, 64, 128, NMAX256, 64, 1);
  // L4: 128->128 @256
  hipLaunchKernelGGL((gconv_k<8, 64, 128, 4, 8, false>), dim3(448, 1, 1), blk, 0, stream,
                     A3, A4, wT[4], Bc[4], nb256, nact + 1, 128, 128, NMAX256, 128, 1);
  hipLaunchKernelGGL(pool_c_k, dim3(NMAX128 * 32 / 256), blk, 0, stream, A4, P4, l128, im256, nact + 2, 256, 128);

  // L5..L13: 8x8 register tile, CC=4, K-split + combine (Praw aliases A1)
  // L5: 128->256 @128, split 2
  hipLaunchKernelGGL((gconv_k<4, 64, 256, 8, 8, true>), dim3(320, 1, 2), blk, 0, stream,
                     P4, Praw, wT[5], nullptr, nb128, nact + 2, 128, 256, NMAX128, 64, 1);
  hipLaunchKernelGGL(combine_k, dim3(NMAX128 * 64 / 256), blk, 0, stream, Praw, A5, Bc[5], nact + 2, 256, 2, NMAX128 * 256);
  // L6: 256->256 @128, split 2
  hipLaunchKernelGGL((gconv_k<4, 64, 256, 8, 8, true>), dim3(320, 1, 2), blk, 0, stream,
                     A5, Praw, wT[6], nullptr, nb128, nact + 2, 256, 256, NMAX128, 128, 1);
  hipLaunchKernelGGL(combine_k, dim3(NMAX128 * 64 / 256), blk, 0, stream, Praw, A6, Bc[6], nact + 2, 256, 2, NMAX128 * 256);
  // L7: 256->256 @128, split 2
  hipLaunchKernelGGL((gconv_k<4, 64, 256, 8, 8, true>), dim3(320, 1, 2), blk, 0, stream,
                     A6, Praw, wT[7], nullptr, nb128, nact + 2, 256, 256, NMAX128, 128, 1);
  hipLaunchKernelGGL(combine_k, dim3(NMAX128 * 64 / 256), blk, 0, stream, Praw, A5, Bc[7], nact + 2, 256, 2, NMAX128 * 256);
  hipLaunchKernelGGL(pool_c_k, dim3(NMAX64 * 64 / 256), blk, 0, stream, A5, P7, l64, im128, nact + 3, 128, 256);
  // L8: 256->512 @64, split 2
  hipLaunchKernelGGL((gconv_k<4, 64, 256, 8, 8, true>), dim3(256, 1, 2), blk, 0, stream,
                     P7, Praw, wT[8], nullptr, nb64, nact + 3, 256, 512, NMAX64, 128, 2);
  hipLaunchKernelGGL(combine_k, dim3(NMAX64 * 128 / 256), blk, 0, stream, Praw, A8, Bc[8], nact + 3, 512, 2, NMAX64 * 512);
  // L9: 512->512 @64, split 4
  hipLaunchKernelGGL((gconv_k<4, 64, 256, 8, 8, true>), dim3(256, 1, 4), blk, 0, stream,
                     A8, Praw, wT[9], nullptr, nb64, nact + 3, 512, 512, NMAX64, 128, 2);
  hipLaunchKernelGGL(combine_k, dim3(NMAX64 * 128 / 256), blk, 0, stream, Praw, A9, Bc[9], nact + 3, 512, 4, NMAX64 * 512);
  // L10: 512->512 @64, split 4
  hipLaunchKernelGGL((gconv_k<4, 64, 256, 8, 8, true>), dim3(256, 1, 4), blk, 0, stream,
                     A9, Praw, wT[10], nullptr, nb64, nact + 3, 512, 512, NMAX64, 128, 2);
  hipLaunchKernelGGL(combine_k, dim3(NMAX64 * 128 / 256), blk, 0, stream, Praw, A8, Bc[10], nact + 3, 512, 4, NMAX64 * 512);
  hipLaunchKernelGGL(pool_c_k, dim3(NMAX32 * 128 / 256), blk, 0, stream, A8, P10, l32, im64, nact + 4, 64, 512);
  // L11-13: 512->512 @32, split 8, A11 reused in place
  hipLaunchKernelGGL((gconv_k<4, 64, 256, 8, 8, true>), dim3(64, 1, 8), blk, 0, stream,
                     P10, Praw, wT[11], nullptr, nb32, nact + 4, 512, 512, NMAX32, 64, 2);
  hipLaunchKernelGGL(combine_k, dim3(NMAX32 * 128 / 256), blk, 0, stream, Praw, A11, Bc[11], nact + 4, 512, 8, NMAX32 * 512);
  hipLaunchKernelGGL((gconv_k<4, 64, 256, 8, 8, true>), dim3(64, 1, 8), blk, 0, stream,
                     A11, Praw, wT[12], nullptr, nb32, nact + 4, 512, 512, NMAX32, 64, 2);
  hipLaunchKernelGGL(combine_k, dim3(NMAX32 * 128 / 256), blk, 0, stream, Praw, A11, Bc[12], nact + 4, 512, 8, NMAX32 * 512);
  hipLaunchKernelGGL((gconv_k<4, 64, 256, 8, 8, true>), dim3(64, 1, 8), blk, 0, stream,
                     A11, Praw, wT[13], nullptr, nb32, nact + 4, 512, 512, NMAX32, 64, 2);
  hipLaunchKernelGGL(combine_k, dim3(NMAX32 * 128 / 256), blk, 0, stream, Praw, A11, Bc[13], nact + 4, 512, 8, NMAX32 * 512);
  // final pool -> dense
  hipLaunchKernelGGL(pool_d_k, dim3(256), blk, 0, stream, A11, D13, im32);

  // ---- MLP
  hipLaunchKernelGGL((fc_k<true>), dim3(1024), blk, 0, stream, D13, fw1, fb1, F1, 131072, 1024);
  hipLaunchKernelGGL((fc_k<true>), dim3(512), blk, 0, stream, F1, fw2, fb2, F2, 1024, 512);
  hipLaunchKernelGGL((fc_k<true>), dim3(256), blk, 0, stream, F2, fw3, fb3, F3, 512, 256);
  hipLaunchKernelGGL((fc_k<false>), dim3(2), blk, 0, stream, F3, fw4, fb4, (float*)d_out, 256, 2);
}

// Round 5
// 4388.220 us; speedup vs baseline: 1.6708x; 1.6708x over previous
//
#include <hip/hip_runtime.h>
#include <cstddef>
#include <cstdint>

#define NB 2

// Nmax per resolution (upper bounds on active sites, both batches)
#define NMAX512 32768
#define NMAX256 28672
#define NMAX128 20480
#define NMAX64  8192
#define NMAX32  2048

// ------------------------------------------------------------------ list build (res 512 from x, Cin=1)
__global__ __launch_bounds__(256) void build_l0_k(const float* __restrict__ x,
    int* __restrict__ list, int* __restrict__ im, float* __restrict__ f0,
    int* __restrict__ nact, int total, int nmax) {
  int i = blockIdx.x * 256 + threadIdx.x;
  bool act = false;
  float v = 0.f;
  if (i < total) { v = x[i]; act = (v != 0.f); }
  unsigned long long mb = __ballot(act);
  int lane = threadIdx.x & 63;
  int prefix = __popcll(mb & ((1ull << lane) - 1));
  int base = 0;
  if (lane == 0) base = atomicAdd(nact, __popcll(mb));
  base = __shfl(base, 0);
  if (i < total) {
    int idx = act ? (base + prefix) : -1;
    if (idx >= nmax) idx = -1;
    im[i] = idx;
    if (idx >= 0) {
      int b = i >> 18;            // 512*512 = 2^18
      int rem = i & 262143;
      list[idx] = (b << 20) | ((rem >> 9) << 10) | (rem & 511);
      f0[idx] = v;
    }
  }
}

// ------------------------------------------------------------------ pooled list from finer idxmap
__global__ __launch_bounds__(256) void build_pl_k(const int* __restrict__ imF,
    int* __restrict__ list, int* __restrict__ im, int* __restrict__ nact,
    int Hc, int nmax) {
  int total = NB * Hc * Hc;
  int i = blockIdx.x * 256 + threadIdx.x;
  bool act = false;
  int b = 0, y = 0, x = 0;
  int Hf = Hc * 2;
  if (i < total) {
    x = i % Hc; y = (i / Hc) % Hc; b = i / (Hc * Hc);
    const int* p = imF + ((size_t)b * Hf + 2 * y) * Hf + 2 * x;
    act = (p[0] >= 0) || (p[1] >= 0) || (p[Hf] >= 0) || (p[Hf + 1] >= 0);
  }
  unsigned long long mb = __ballot(act);
  int lane = threadIdx.x & 63;
  int prefix = __popcll(mb & ((1ull << lane) - 1));
  int base = 0;
  if (lane == 0) base = atomicAdd(nact, __popcll(mb));
  base = __shfl(base, 0);
  if (i < total) {
    int idx = act ? (base + prefix) : -1;
    if (idx >= nmax) idx = -1;
    im[i] = idx;
    if (idx >= 0) list[idx] = (b << 20) | (y << 10) | x;
  }
}

// ------------------------------------------------------------------ 9-neighbor index table
__global__ __launch_bounds__(256) void build_nbr_k(const int* __restrict__ list,
    const int* __restrict__ im, const int* __restrict__ nactp,
    int* __restrict__ nbr, int H, int nmax) {
  int i = blockIdx.x * 256 + threadIdx.x;
  if (i >= nactp[0]) return;
  int code = list[i];
  int b = code >> 20, y = (code >> 10) & 1023, x = code & 1023;
#pragma unroll
  for (int k = 0; k < 9; ++k) {
    int yy = y + k / 3 - 1, xx = x + k % 3 - 1;
    int v = -1;
    if (yy >= 0 && yy < H && xx >= 0 && xx < H)
      v = im[((size_t)b * H + yy) * H + xx];
    nbr[k * nmax + i] = v;
  }
}

// ------------------------------------------------------------------ weight transpose  [R][C] -> [C][R]
__global__ __launch_bounds__(256) void transpose_k(const float* __restrict__ in,
                                                   float* __restrict__ out,
                                                   int R, int C) {
  __shared__ float tile[32][33];
  int bx = blockIdx.x * 32;  // col base (C dim)
  int by = blockIdx.y * 32;  // row base (R dim)
  int tx = threadIdx.x % 32, ty0 = threadIdx.x / 32;
  for (int ty = ty0; ty < 32; ty += 8) {
    int r = by + ty, c = bx + tx;
    tile[ty][tx] = (r < R && c < C) ? in[(size_t)r * C + c] : 0.f;
  }
  __syncthreads();
  for (int ty = ty0; ty < 32; ty += 8) {
    int r = bx + ty, c = by + tx;
    if (r < C && c < R) out[(size_t)r * R + c] = tile[tx][ty];
  }
}

// ------------------------------------------------------------------ gather-GEMM submanifold conv
// Block: SITES sites x OCB out-channels; thread: SPT sites x OPT oc.
// OPT==8 split-oc: thread owns {oc0..+3} u {OCB/2+oc0..+3} -> wave LDS reads
// are contiguous 16B chunks (<=2-way alias = free).
// SPT==8: a-read is 2x b128 (broadcast across oc-groups).
// XCD swizzle: gid=(sbg*nocb+ocbI)*8+xcd so all panels of one site-block
// share gid mod 8 (same XCD L2).
// NOTE (round-4 lesson): RAW K-split partial streams through L2 destroy the
// weight-panel reuse (FETCH 58MB -> 1.17GB); heavy layers must write once.
template <int CC, int SITES, int OCB, int SPT, int OPT, bool RAW>
__global__ __launch_bounds__(256, 2) void gconv_k(
    const float* __restrict__ in, float* __restrict__ out,
    const float* __restrict__ wT, const float* __restrict__ bias,
    const int* __restrict__ nbr, const int* __restrict__ nactp,
    int Cin, int Cout, int Nmax, int cinCnt, int nocb) {
  constexpr int KSL = CC * 9;
  __shared__ int s_nbr[9][SITES];
  __shared__ float s_a[KSL][SITES];
  __shared__ float s_w[KSL][OCB];
  const int n = nactp[0];
  const int gid = blockIdx.x;
  const int xcd = gid & 7;
  const int pos = gid >> 3;
  const int ocbI = pos % nocb;
  const int sb = (pos / nocb) * 8 + xcd;
  const int base = sb * SITES;
  if (base >= n) return;
  const int ocb = ocbI * OCB;
  const int t = threadIdx.x;
  for (int s = t; s < 9 * SITES; s += 256) {
    int i = s % SITES, k = s / SITES;
    int gi = base + i;
    s_nbr[k][i] = (gi < n) ? nbr[k * Nmax + gi] : -1;
  }
  constexpr int OCG = OCB / OPT;
  const int oc0 = (t % OCG) * 4;           // 4-float chunk base
  const int si0 = (t / OCG) * SPT;
  float acc[SPT][OPT];
#pragma unroll
  for (int a = 0; a < SPT; ++a)
#pragma unroll
    for (int j = 0; j < OPT; ++j) acc[a][j] = 0.f;
  __syncthreads();
  const int cinStart = RAW ? (blockIdx.z * cinCnt) : 0;
  const int nch = cinCnt / CC;
  for (int ch = 0; ch < nch; ++ch) {
    const int c0 = cinStart + ch * CC;
    // ---- stage weights: KSL contiguous rows of wT starting at row c0*9 (float4)
    const float* wrow = wT + ((size_t)c0 * 9) * Cout + ocb;
    for (int s = t; s < KSL * (OCB / 4); s += 256) {
      int j4 = s % (OCB / 4), r = s / (OCB / 4);
      *(float4*)&s_w[r][j4 * 4] = *(const float4*)(wrow + (size_t)r * Cout + j4 * 4);
    }
    // ---- stage gathered A tile
    if constexpr (CC == 1) {
      for (int s = t; s < 9 * SITES; s += 256) {
        int i = s % SITES, k = s / SITES;
        int row = s_nbr[k][i];
        s_a[k][i] = (row >= 0) ? in[row] : 0.f;
      }
    } else {
      constexpr int H4 = CC / 4;
      for (int s = t; s < H4 * 9 * SITES; s += 256) {
        int i = s % SITES, m = s / SITES;
        int c4 = m % H4, k = m / H4;
        int row = s_nbr[k][i];
        float4 v = make_float4(0.f, 0.f, 0.f, 0.f);
        if (row >= 0)
          v = *(const float4*)(in + (size_t)row * Cin + c0 + c4 * 4);
        s_a[(c4 * 4 + 0) * 9 + k][i] = v.x;
        s_a[(c4 * 4 + 1) * 9 + k][i] = v.y;
        s_a[(c4 * 4 + 2) * 9 + k][i] = v.z;
        s_a[(c4 * 4 + 3) * 9 + k][i] = v.w;
      }
    }
    __syncthreads();
    // ---- MAC
#pragma unroll
    for (int kk = 0; kk < KSL; ++kk) {
      float av[SPT];
      if constexpr (SPT == 8) {
        float4 a0 = *(const float4*)&s_a[kk][si0];
        float4 a1 = *(const float4*)&s_a[kk][si0 + 4];
        av[0] = a0.x; av[1] = a0.y; av[2] = a0.z; av[3] = a0.w;
        av[4] = a1.x; av[5] = a1.y; av[6] = a1.z; av[7] = a1.w;
      } else if constexpr (SPT == 4) {
        float4 a4 = *(const float4*)&s_a[kk][si0];
        av[0] = a4.x; av[1] = a4.y; av[2] = a4.z; av[3] = a4.w;
      } else {
        float2 a2 = *(const float2*)&s_a[kk][si0];
        av[0] = a2.x; av[1] = a2.y;
      }
      float wv[OPT];
      if constexpr (OPT == 8) {
        float4 w4a = *(const float4*)&s_w[kk][oc0];
        float4 w4b = *(const float4*)&s_w[kk][OCB / 2 + oc0];
        wv[0] = w4a.x; wv[1] = w4a.y; wv[2] = w4a.z; wv[3] = w4a.w;
        wv[4] = w4b.x; wv[5] = w4b.y; wv[6] = w4b.z; wv[7] = w4b.w;
      } else {
        float4 w4 = *(const float4*)&s_w[kk][oc0];
        wv[0] = w4.x; wv[1] = w4.y; wv[2] = w4.z; wv[3] = w4.w;
      }
#pragma unroll
      for (int a = 0; a < SPT; ++a)
#pragma unroll
        for (int j = 0; j < OPT; ++j)
          acc[a][j] = fmaf(av[a], wv[j], acc[a][j]);
    }
    __syncthreads();
  }
  // ---- epilogue
  float bz[OPT];
  if constexpr (!RAW) {
#pragma unroll
    for (int j = 0; j < OPT; ++j) {
      int oj = (OPT == 8) ? ((j < 4) ? (oc0 + j) : (OCB / 2 + oc0 + j - 4))
                          : (oc0 + j);
      bz[j] = bias[ocb + oj];
    }
  }
  float* ob = out;
  if constexpr (RAW) ob += (size_t)blockIdx.z * Nmax * Cout;
#pragma unroll
  for (int a = 0; a < SPT; ++a) {
    int gi = base + si0 + a;
    if (gi < n) {
      float* po = ob + (size_t)gi * Cout + ocb;
      if constexpr (OPT == 8) {
        float4 v0, v1;
        if constexpr (RAW) {
          v0 = make_float4(acc[a][0], acc[a][1], acc[a][2], acc[a][3]);
          v1 = make_float4(acc[a][4], acc[a][5], acc[a][6], acc[a][7]);
        } else {
          v0.x = fmaxf(acc[a][0] + bz[0], 0.f); v0.y = fmaxf(acc[a][1] + bz[1], 0.f);
          v0.z = fmaxf(acc[a][2] + bz[2], 0.f); v0.w = fmaxf(acc[a][3] + bz[3], 0.f);
          v1.x = fmaxf(acc[a][4] + bz[4], 0.f); v1.y = fmaxf(acc[a][5] + bz[5], 0.f);
          v1.z = fmaxf(acc[a][6] + bz[6], 0.f); v1.w = fmaxf(acc[a][7] + bz[7], 0.f);
        }
        *(float4*)(po + oc0) = v0;
        *(float4*)(po + OCB / 2 + oc0) = v1;
      } else {
        float4 v;
        if constexpr (RAW) {
          v = make_float4(acc[a][0], acc[a][1], acc[a][2], acc[a][3]);
        } else {
          v.x = fmaxf(acc[a][0] + bz[0], 0.f); v.y = fmaxf(acc[a][1] + bz[1], 0.f);
          v.z = fmaxf(acc[a][2] + bz[2], 0.f); v.w = fmaxf(acc[a][3] + bz[3], 0.f);
        }
        *(float4*)(po + oc0) = v;
      }
    }
  }
}

// ------------------------------------------------------------------ K-split combine (+bias+relu)
__global__ __launch_bounds__(256) void combine_k(const float* __restrict__ P,
    float* __restrict__ out, const float* __restrict__ bias,
    const int* __restrict__ nactp, int C, int S, int sliceStride) {
  int tg = blockIdx.x * 256 + threadIdx.x;
  int cg = C >> 2;
  int j = tg / cg, c4 = tg % cg;
  if (j >= nactp[0]) return;
  size_t o = (size_t)j * C + c4 * 4;
  float4 v = *(const float4*)(bias + c4 * 4);
  for (int s = 0; s < S; ++s) {
    float4 u = *(const float4*)(P + (size_t)s * sliceStride + o);
    v.x += u.x; v.y += u.y; v.z += u.z; v.w += u.w;
  }
  v.x = fmaxf(v.x, 0.f); v.y = fmaxf(v.y, 0.f);
  v.z = fmaxf(v.z, 0.f); v.w = fmaxf(v.w, 0.f);
  *(float4*)(out + o) = v;
}

// ------------------------------------------------------------------ compact 2x2 maxpool
__global__ __launch_bounds__(256) void pool_c_k(const float* __restrict__ inF,
    float* __restrict__ outF, const int* __restrict__ listC,
    const int* __restrict__ imF, const int* __restrict__ nactp, int Hf, int C) {
  int tg = blockIdx.x * 256 + threadIdx.x;
  int cg = C >> 2;
  int j = tg / cg, c4 = tg % cg;
  if (j >= nactp[0]) return;
  int code = listC[j];
  int b = code >> 20, Y = (code >> 10) & 1023, X = code & 1023;
  float4 v = make_float4(0.f, 0.f, 0.f, 0.f);
#pragma unroll
  for (int dy = 0; dy < 2; ++dy)
#pragma unroll
    for (int dx = 0; dx < 2; ++dx) {
      int ci = imF[((size_t)b * Hf + 2 * Y + dy) * Hf + 2 * X + dx];
      if (ci >= 0) {
        float4 u = *(const float4*)(inF + (size_t)ci * C + c4 * 4);
        v.x = fmaxf(v.x, u.x); v.y = fmaxf(v.y, u.y);
        v.z = fmaxf(v.z, u.z); v.w = fmaxf(v.w, u.w);
      }
    }
  *(float4*)(outF + (size_t)j * C + c4 * 4) = v;
}

// ------------------------------------------------------------------ final pool -> dense [2,512,16,16]
__global__ __launch_bounds__(256) void pool_d_k(const float* __restrict__ inF,
    float* __restrict__ outD, const int* __restrict__ im32) {
  int tg = blockIdx.x * 256 + threadIdx.x;  // 2*16*16*128 = 65536
  int c4 = tg & 127;
  int rest = tg >> 7;
  int X = rest & 15, Y = (rest >> 4) & 15, b = rest >> 8;
  float4 v = make_float4(0.f, 0.f, 0.f, 0.f);
#pragma unroll
  for (int dy = 0; dy < 2; ++dy)
#pragma unroll
    for (int dx = 0; dx < 2; ++dx) {
      int ci = im32[((size_t)b * 32 + 2 * Y + dy) * 32 + 2 * X + dx];
      if (ci >= 0) {
        float4 u = *(const float4*)(inF + (size_t)ci * 512 + c4 * 4);
        v.x = fmaxf(v.x, u.x); v.y = fmaxf(v.y, u.y);
        v.z = fmaxf(v.z, u.z); v.w = fmaxf(v.w, u.w);
      }
    }
  const float* pv = &v.x;
#pragma unroll
  for (int u = 0; u < 4; ++u) {
    int c = c4 * 4 + u;
    outD[(((size_t)b * 512 + c) * 16 + Y) * 16 + X] = pv[u];
  }
}

// ------------------------------------------------------------------ fully connected
template <bool RELU>
__global__ __launch_bounds__(256) void fc_k(const float* __restrict__ in,
                                            const float* __restrict__ w,
                                            const float* __restrict__ bias,
                                            float* __restrict__ out, int K,
                                            int R) {
  const int r = blockIdx.x;
  const int t = threadIdx.x;
  const float* wr = w + (size_t)r * K;
  float a0 = 0.f, a1 = 0.f;
  for (int k = t * 4; k < K; k += 1024) {
    float4 wv = *(const float4*)(wr + k);
    float4 x0 = *(const float4*)(in + k);
    float4 x1 = *(const float4*)(in + K + k);
    a0 += wv.x * x0.x + wv.y * x0.y + wv.z * x0.z + wv.w * x0.w;
    a1 += wv.x * x1.x + wv.y * x1.y + wv.z * x1.z + wv.w * x1.w;
  }
#pragma unroll
  for (int off = 32; off > 0; off >>= 1) {
    a0 += __shfl_down(a0, off);
    a1 += __shfl_down(a1, off);
  }
  __shared__ float s0[4], s1[4];
  const int lane = t & 63, wid = t >> 6;
  if (lane == 0) { s0[wid] = a0; s1[wid] = a1; }
  __syncthreads();
  if (t == 0) {
    float v0 = s0[0] + s0[1] + s0[2] + s0[3] + bias[r];
    float v1 = s1[0] + s1[1] + s1[2] + s1[3] + bias[r];
    if (RELU) { v0 = fmaxf(v0, 0.f); v1 = fmaxf(v1, 0.f); }
    out[r] = v0;
    out[R + r] = v1;
  }
}

// ------------------------------------------------------------------ launch
extern "C" void kernel_launch(void* const* d_in, const int* in_sizes, int n_in,
                              void* d_out, int out_size, void* d_ws,
                              size_t ws_size, hipStream_t stream) {
  (void)in_sizes; (void)n_in; (void)out_size; (void)ws_size;
  const float* x = (const float*)d_in[0];
  const float* Wc[14];
  const float* Bc[14];
  for (int i = 1; i <= 13; ++i) {
    Wc[i] = (const float*)d_in[2 * i - 1];
    Bc[i] = (const float*)d_in[2 * i];
  }
  const float* fw1 = (const float*)d_in[27];
  const float* fb1 = (const float*)d_in[28];
  const float* fw2 = (const float*)d_in[29];
  const float* fb2 = (const float*)d_in[30];
  const float* fw3 = (const float*)d_in[31];
  const float* fb3 = (const float*)d_in[32];
  const float* fw4 = (const float*)d_in[33];
  const float* fb4 = (const float*)d_in[34];

  static const int CH[14] = {1, 64, 64, 128, 128, 256, 256, 256,
                             512, 512, 512, 512, 512, 512};

  char* ws = (char*)d_ws;
  size_t cur = 0;
  auto alloc = [&](size_t bytes) {
    size_t o = cur;
    cur += (bytes + 255) & ~(size_t)255;
    return o;
  };
  // weight transposes
  size_t wtOff[14];
  for (int i = 1; i <= 13; ++i)
    wtOff[i] = alloc((size_t)CH[i] * CH[i - 1] * 9 * 4);
  float* wT[14];
  for (int i = 1; i <= 13; ++i) wT[i] = (float*)(ws + wtOff[i]);
  // features
  float* F0  = (float*)(ws + alloc((size_t)NMAX512 * 1 * 4));
  float* A1  = (float*)(ws + alloc((size_t)NMAX512 * 64 * 4));
  float* A2  = (float*)(ws + alloc((size_t)NMAX512 * 64 * 4));
  float* P2  = (float*)(ws + alloc((size_t)NMAX256 * 64 * 4));
  float* A3  = (float*)(ws + alloc((size_t)NMAX256 * 128 * 4));
  float* A4  = (float*)(ws + alloc((size_t)NMAX256 * 128 * 4));
  float* P4  = (float*)(ws + alloc((size_t)NMAX128 * 128 * 4));
  float* A5  = (float*)(ws + alloc((size_t)NMAX128 * 256 * 4));
  float* A6  = (float*)(ws + alloc((size_t)NMAX128 * 256 * 4));
  float* P7  = (float*)(ws + alloc((size_t)NMAX64 * 256 * 4));
  float* A8  = (float*)(ws + alloc((size_t)NMAX64 * 512 * 4));
  float* A9  = (float*)(ws + alloc((size_t)NMAX64 * 512 * 4));  // also Praw for L11-13
  float* P10 = (float*)(ws + alloc((size_t)NMAX32 * 512 * 4));
  float* A11 = (float*)(ws + alloc((size_t)NMAX32 * 512 * 4));
  float* A12 = (float*)(ws + alloc((size_t)NMAX32 * 512 * 4));
  float* D13 = (float*)(ws + alloc((size_t)NB * 512 * 16 * 16 * 4));
  float* F1  = (float*)(ws + alloc(NB * 1024 * 4));
  float* F2  = (float*)(ws + alloc(NB * 512 * 4));
  float* F3  = (float*)(ws + alloc(NB * 256 * 4));
  // index maps / lists / neighbor tables / counters
  int* im512 = (int*)(ws + alloc((size_t)NB * 512 * 512 * 4));
  int* im256 = (int*)(ws + alloc((size_t)NB * 256 * 256 * 4));
  int* im128 = (int*)(ws + alloc((size_t)NB * 128 * 128 * 4));
  int* im64  = (int*)(ws + alloc((size_t)NB * 64 * 64 * 4));
  int* im32  = (int*)(ws + alloc((size_t)NB * 32 * 32 * 4));
  int* l512 = (int*)(ws + alloc((size_t)NMAX512 * 4));
  int* l256 = (int*)(ws + alloc((size_t)NMAX256 * 4));
  int* l128 = (int*)(ws + alloc((size_t)NMAX128 * 4));
  int* l64  = (int*)(ws + alloc((size_t)NMAX64 * 4));
  int* l32  = (int*)(ws + alloc((size_t)NMAX32 * 4));
  int* nb512 = (int*)(ws + alloc((size_t)9 * NMAX512 * 4));
  int* nb256 = (int*)(ws + alloc((size_t)9 * NMAX256 * 4));
  int* nb128 = (int*)(ws + alloc((size_t)9 * NMAX128 * 4));
  int* nb64  = (int*)(ws + alloc((size_t)9 * NMAX64 * 4));
  int* nb32  = (int*)(ws + alloc((size_t)9 * NMAX32 * 4));
  int* nact = (int*)(ws + alloc(256));  // [0..4] per-resolution counts

  const dim3 blk(256);
  hipMemsetAsync(nact, 0, 32, stream);

  // ---- lists / index maps / neighbors
  hipLaunchKernelGGL(build_l0_k, dim3(2048), blk, 0, stream, x, l512, im512, F0, nact + 0, NB * 512 * 512, NMAX512);
  hipLaunchKernelGGL(build_pl_k, dim3(512), blk, 0, stream, im512, l256, im256, nact + 1, 256, NMAX256);
  hipLaunchKernelGGL(build_pl_k, dim3(128), blk, 0, stream, im256, l128, im128, nact + 2, 128, NMAX128);
  hipLaunchKernelGGL(build_pl_k, dim3(32), blk, 0, stream, im128, l64, im64, nact + 3, 64, NMAX64);
  hipLaunchKernelGGL(build_pl_k, dim3(8), blk, 0, stream, im64, l32, im32, nact + 4, 32, NMAX32);
  hipLaunchKernelGGL(build_nbr_k, dim3(NMAX512 / 256), blk, 0, stream, l512, im512, nact + 0, nb512, 512, NMAX512);
  hipLaunchKernelGGL(build_nbr_k, dim3(NMAX256 / 256), blk, 0, stream, l256, im256, nact + 1, nb256, 256, NMAX256);
  hipLaunchKernelGGL(build_nbr_k, dim3(NMAX128 / 256), blk, 0, stream, l128, im128, nact + 2, nb128, 128, NMAX128);
  hipLaunchKernelGGL(build_nbr_k, dim3(NMAX64 / 256), blk, 0, stream, l64, im64, nact + 3, nb64, 64, NMAX64);
  hipLaunchKernelGGL(build_nbr_k, dim3(NMAX32 / 256), blk, 0, stream, l32, im32, nact + 4, nb32, 32, NMAX32);

  // ---- weight transposes: w[Cout][Cin*9] -> wT[Cin*9][Cout]
  for (int i = 1; i <= 13; ++i) {
    int R = CH[i], C = CH[i - 1] * 9;
    hipLaunchKernelGGL(transpose_k, dim3((C + 31) / 32, (R + 31) / 32), blk, 0,
                       stream, Wc[i], wT[i], R, C);
  }

  // ---- convs
  // L1: 1->64 @512
  hipLaunchKernelGGL((gconv_k<1, 64, 64, 4, 4, false>), dim3(512, 1, 1), blk, 0, stream,
                     F0, A1, wT[1], Bc[1], nb512, nact + 0, 1, 64, NMAX512, 1, 1);
  // L2: 64->64 @512
  hipLaunchKernelGGL((gconv_k<8, 64, 64, 4, 4, false>), dim3(512, 1, 1), blk, 0, stream,
                     A1, A2, wT[2], Bc[2], nb512, nact + 0, 64, 64, NMAX512, 64, 1);
  hipLaunchKernelGGL(pool_c_k, dim3(NMAX256 * 16 / 256), blk, 0, stream, A2, P2, l256, im512, nact + 1, 512, 64);
  // L3: 64->128 @256
  hipLaunchKernelGGL((gconv_k<8, 64, 128, 4, 8, false>), dim3(448, 1, 1), blk, 0, stream,
                     P2, A3, wT[3], Bc[3], nb256, nact + 1, 64, 128, NMAX256, 64, 1);
  // L4: 128->128 @256
  hipLaunchKernelGGL((gconv_k<8, 64, 128, 4, 8, false>), dim3(448, 1, 1), blk, 0, stream,
                     A3, A4, wT[4], Bc[4], nb256, nact + 1, 128, 128, NMAX256, 128, 1);
  hipLaunchKernelGGL(pool_c_k, dim3(NMAX128 * 32 / 256), blk, 0, stream, A4, P4, l128, im256, nact + 2, 256, 128);

  // L5..L10: 8x8 register tile at SITES=128 x OCB=128, non-RAW, full-K per block
  // L5: 128->256 @128  (nsb=160 -> grid 20*2*8=320)
  hipLaunchKernelGGL((gconv_k<8, 128, 128, 8, 8, false>), dim3(320, 1, 1), blk, 0, stream,
                     P4, A5, wT[5], Bc[5], nb128, nact + 2, 128, 256, NMAX128, 128, 2);
  // L6: 256->256 @128
  hipLaunchKernelGGL((gconv_k<8, 128, 128, 8, 8, false>), dim3(320, 1, 1), blk, 0, stream,
                     A5, A6, wT[6], Bc[6], nb128, nact + 2, 256, 256, NMAX128, 256, 2);
  // L7: 256->256 @128
  hipLaunchKernelGGL((gconv_k<8, 128, 128, 8, 8, false>), dim3(320, 1, 1), blk, 0, stream,
                     A6, A5, wT[7], Bc[7], nb128, nact + 2, 256, 256, NMAX128, 256, 2);
  hipLaunchKernelGGL(pool_c_k, dim3(NMAX64 * 64 / 256), blk, 0, stream, A5, P7, l64, im128, nact + 3, 128, 256);
  // L8: 256->512 @64  (nsb=64 -> grid 8*4*8=256)
  hipLaunchKernelGGL((gconv_k<8, 128, 128, 8, 8, false>), dim3(256, 1, 1), blk, 0, stream,
                     P7, A8, wT[8], Bc[8], nb64, nact + 3, 256, 512, NMAX64, 256, 4);
  // L9: 512->512 @64
  hipLaunchKernelGGL((gconv_k<8, 128, 128, 8, 8, false>), dim3(256, 1, 1), blk, 0, stream,
                     A8, A9, wT[9], Bc[9], nb64, nact + 3, 512, 512, NMAX64, 512, 4);
  // L10: 512->512 @64
  hipLaunchKernelGGL((gconv_k<8, 128, 128, 8, 8, false>), dim3(256, 1, 1), blk, 0, stream,
                     A9, A8, wT[10], Bc[10], nb64, nact + 3, 512, 512, NMAX64, 512, 4);
  hipLaunchKernelGGL(pool_c_k, dim3(NMAX32 * 128 / 256), blk, 0, stream, A8, P10, l32, im64, nact + 4, 64, 512);

  // L11-13: 512->512 @32, round-3 structure (RAW split-4 into A9 + combine;
  // small partial volume is L2-friendly here)
  const int SLICE = NMAX32 * 512;
  hipLaunchKernelGGL((gconv_k<8, 64, 128, 4, 8, true>), dim3(32 * 4, 1, 4), blk, 0, stream,
                     P10, A9, wT[11], nullptr, nb32, nact + 4, 512, 512, NMAX32, 128, 4);
  hipLaunchKernelGGL(combine_k, dim3(NMAX32 * 128 / 256), blk, 0, stream, A9, A11, Bc[11], nact + 4, 512, 4, SLICE);
  hipLaunchKernelGGL((gconv_k<8, 64, 128, 4, 8, true>), dim3(32 * 4, 1, 4), blk, 0, stream,
                     A11, A9, wT[12], nullptr, nb32, nact + 4, 512, 512, NMAX32, 128, 4);
  hipLaunchKernelGGL(combine_k, dim3(NMAX32 * 128 / 256), blk, 0, stream, A9, A12, Bc[12], nact + 4, 512, 4, SLICE);
  hipLaunchKernelGGL((gconv_k<8, 64, 128, 4, 8, true>), dim3(32 * 4, 1, 4), blk, 0, stream,
                     A12, A9, wT[13], nullptr, nb32, nact + 4, 512, 512, NMAX32, 128, 4);
  hipLaunchKernelGGL(combine_k, dim3(NMAX32 * 128 / 256), blk, 0, stream, A9, A11, Bc[13], nact + 4, 512, 4, SLICE);
  // final pool -> dense
  hipLaunchKernelGGL(pool_d_k, dim3(256), blk, 0, stream, A11, D13, im32);

  // ---- MLP
  hipLaunchKernelGGL((fc_k<true>), dim3(1024), blk, 0, stream, D13, fw1, fb1, F1, 131072, 1024);
  hipLaunchKernelGGL((fc_k<true>), dim3(512), blk, 0, stream, F1, fw2, fb2, F2, 1024, 512);
  hipLaunchKernelGGL((fc_k<true>), dim3(256), blk, 0, stream, F2, fw3, fb3, F3, 512, 256);
  hipLaunchKernelGGL((fc_k<false>), dim3(2), blk, 0, stream, F3, fw4, fb4, (float*)d_out, 256, 2);
}